// Round 1
// baseline (2565.150 us; speedup 1.0000x reference)
//
#include <hip/hip_runtime.h>

#define NS 200000
#define NK 27
#define EPSV 1e-5f

typedef __bf16 bf16x8 __attribute__((ext_vector_type(8)));
typedef float f32x4 __attribute__((ext_vector_type(4)));
typedef unsigned short u16;
typedef u16 u16x8 __attribute__((ext_vector_type(8)));
typedef u16 u16x4 __attribute__((ext_vector_type(4)));

__device__ __forceinline__ u16 f2bf(float f) {
  union { float f; unsigned u; } v; v.f = f;
  unsigned r = v.u + 0x7fffu + ((v.u >> 16) & 1u);
  return (u16)(r >> 16);
}
__device__ __forceinline__ float bf2f(u16 u) {
  union { unsigned u; float f; } v; v.u = ((unsigned)u) << 16;
  return v.f;
}

// ---- prep: zero stats, feats f32 -> bf16 with zero row at N ----
__global__ void k_prep_x(const float* __restrict__ feats, u16* __restrict__ Xbf,
                         float* __restrict__ stats) {
  long i = (long)blockIdx.x * 256 + threadIdx.x;
  if (i < 768) stats[i] = 0.f;
  const long total = (long)(NS + 1) * 64;
  if (i < total) {
    long row = i >> 6;
    Xbf[i] = (row < NS) ? f2bf(feats[i]) : (u16)0;
  }
}

// ---- pack W [K][C][128] f32 -> MFMA-B-fragment-ordered bf16 ----
// packed index f = ((k*S+s)*8+cf)*512 + r*32 + q*8 + j  <->  W[k][s*32+q*8+j][cf*16+r]
__global__ void k_pack_w(const float* __restrict__ W1, const float* __restrict__ W2,
                         const float* __restrict__ Wsc, u16* __restrict__ Wp1,
                         u16* __restrict__ Wp2, u16* __restrict__ Wpsc) {
  int i = blockIdx.x * 256 + threadIdx.x;
  const int n1 = NK * 64 * 128, n2 = NK * 128 * 128, n3 = 64 * 128;
  const float* src; u16* dst; int f, S, C;
  if (i < n1)            { src = W1;  dst = Wp1;  f = i;            S = 2; C = 64; }
  else if (i < n1 + n2)  { src = W2;  dst = Wp2;  f = i - n1;       S = 4; C = 128; }
  else if (i < n1 + n2 + n3) { src = Wsc; dst = Wpsc; f = i - n1 - n2; S = 2; C = 64; }
  else return;
  int j = f & 7, q = (f >> 3) & 3, r = (f >> 5) & 15, cf = (f >> 9) & 7;
  int rest = f >> 12;
  int s = rest % S, k = rest / S;
  int kk = s * 32 + q * 8 + j;
  dst[f] = f2bf(src[(k * C + kk) * 128 + cf * 16 + r]);
}

// ---- gather-GEMM sparse conv: 64 output rows/block, 4 waves, 16 rows/wave ----
template <int C, bool FUSE_SC>
__global__ __launch_bounds__(256) void k_spconv(
    const u16* __restrict__ X, const u16* __restrict__ Wp, const u16* __restrict__ Wpsc,
    const int* __restrict__ in_idx, const int* __restrict__ out_idx,
    u16* __restrict__ Ybf, u16* __restrict__ SCbf) {
  constexpr int S = C / 32;   // 32-deep K slices
  constexpr int CPR = C / 8;  // 16B chunks per row
  constexpr int LG = (C == 64) ? 3 : 4;
  __shared__ alignas(16) u16 Xs[64 * C];
  const int t = threadIdx.x;
  const int w = t >> 6;
  const int l = t & 63;
  const int lr = l & 15, lh = l >> 4;
  const int base = blockIdx.x * 64;
  const int laneoff = lr * 32 + lh * 8;  // packed-W per-lane element offset
  const int myrow = w * 16 + lr;         // tile-local row this lane's A-frag uses

  f32x4 acc[8];
  f32x4 accsc[FUSE_SC ? 8 : 1];
  #pragma unroll
  for (int i = 0; i < 8; ++i) acc[i] = (f32x4){0.f, 0.f, 0.f, 0.f};
  if constexpr (FUSE_SC) {
    #pragma unroll
    for (int i = 0; i < 8; ++i) accsc[i] = (f32x4){0.f, 0.f, 0.f, 0.f};
  }

  for (int k = 0; k < NK; ++k) {
    __syncthreads();
    // stage gathered rows into LDS (XOR-swizzled on 16B chunks within a row)
    #pragma unroll
    for (int it = 0; it < (64 * CPR) / 256; ++it) {
      int c = it * 256 + t;
      int row = c >> LG;
      int c8l = c & (CPR - 1);
      int c8 = (c8l & ~7) | ((c8l ^ row) & 7);
      int gi = k * NS + base + row;
      int oi = out_idx[gi];
      int srcr = (oi != NS) ? in_idx[gi] : NS;  // invalid -> zero row N
      bf16x8 v = *reinterpret_cast<const bf16x8*>(X + (long)srcr * C + c8 * 8);
      *reinterpret_cast<bf16x8*>(Xs + c * 8) = v;
    }
    __syncthreads();
    #pragma unroll
    for (int s = 0; s < S; ++s) {
      int chunk = s * 4 + lh;
      int lchunk = (chunk & ~7) | ((chunk ^ myrow) & 7);
      bf16x8 a = *reinterpret_cast<const bf16x8*>(Xs + (myrow * CPR + lchunk) * 8);
      const u16* wb = Wp + ((long)(k * S + s) * 8) * 512 + laneoff;
      #pragma unroll
      for (int cf = 0; cf < 8; ++cf) {
        bf16x8 b = *reinterpret_cast<const bf16x8*>(wb + cf * 512);
        acc[cf] = __builtin_amdgcn_mfma_f32_16x16x32_bf16(a, b, acc[cf], 0, 0, 0);
      }
      if constexpr (FUSE_SC) {
        if (k == 13) {  // center offset: staged tile IS the identity gather
          const u16* wsp = Wpsc + (long)s * 8 * 512 + laneoff;
          #pragma unroll
          for (int cf = 0; cf < 8; ++cf) {
            bf16x8 b = *reinterpret_cast<const bf16x8*>(wsp + cf * 512);
            accsc[cf] = __builtin_amdgcn_mfma_f32_16x16x32_bf16(a, b, accsc[cf], 0, 0, 0);
          }
        }
      }
    }
  }
  // epilogue: C/D layout col=l&15, row=(l>>4)*4+r
  #pragma unroll
  for (int cf = 0; cf < 8; ++cf) {
    #pragma unroll
    for (int r = 0; r < 4; ++r) {
      long row = base + w * 16 + lh * 4 + r;
      int ch = cf * 16 + lr;
      Ybf[row * 128 + ch] = f2bf(acc[cf][r]);
      if constexpr (FUSE_SC) SCbf[row * 128 + ch] = f2bf(accsc[cf][r]);
    }
  }
}

// ---- per-channel sum / sumsq over N rows (bf16 input) ----
template <bool DUAL>
__global__ void k_stats(const u16* __restrict__ A, const u16* __restrict__ B,
                        float* __restrict__ sA, float* __restrict__ sB) {
  int t = threadIdx.x;
  int ch = t & 127, half = t >> 7;
  float s1 = 0.f, q1 = 0.f, s2 = 0.f, q2 = 0.f;
  for (long r = blockIdx.x * 2 + half; r < NS; r += 128) {
    float v = bf2f(A[r * 128 + ch]); s1 += v; q1 += v * v;
    if (DUAL) { float u = bf2f(B[r * 128 + ch]); s2 += u; q2 += u * u; }
  }
  __shared__ float red[256];
  red[t] = s1; __syncthreads();
  if (t < 128) atomicAdd(&sA[t], red[t] + red[t + 128]);
  __syncthreads(); red[t] = q1; __syncthreads();
  if (t < 128) atomicAdd(&sA[128 + t], red[t] + red[t + 128]);
  if (DUAL) {
    __syncthreads(); red[t] = s2; __syncthreads();
    if (t < 128) atomicAdd(&sB[t], red[t] + red[t + 128]);
    __syncthreads(); red[t] = q2; __syncthreads();
    if (t < 128) atomicAdd(&sB[128 + t], red[t] + red[t + 128]);
  }
}

// ---- h = relu(bn1(y1)) -> bf16 (+ zero dummy row N) ----
__global__ void k_bnrelu(const u16* __restrict__ Y1, const float* __restrict__ stats,
                         const float* __restrict__ g, const float* __restrict__ b,
                         u16* __restrict__ H) {
  long i8 = (long)blockIdx.x * 256 + threadIdx.x;
  const long tot = (long)(NS + 1) * 16;
  if (i8 >= tot) return;
  long row = i8 >> 4;
  u16x8 o;
  if (row < NS) {
    int ch0 = ((int)i8 & 15) * 8;
    u16x8 y = *reinterpret_cast<const u16x8*>(Y1 + i8 * 8);
    #pragma unroll
    for (int e = 0; e < 8; ++e) {
      int ch = ch0 + e;
      float m = stats[ch] * (1.f / NS);
      float var = stats[128 + ch] * (1.f / NS) - m * m;
      float a = g[ch] * rsqrtf(var + EPSV);
      float bb = b[ch] - m * a;
      float h = bf2f(y[e]) * a + bb;
      o[e] = f2bf(h > 0.f ? h : 0.f);
    }
  } else {
    #pragma unroll
    for (int e = 0; e < 8; ++e) o[e] = (u16)0;
  }
  *reinterpret_cast<u16x8*>(H + i8 * 8) = o;
}

// ---- out = relu(bn2(y2) + bnsc(sc)) f32 ----
__global__ void k_final(const u16* __restrict__ Y2, const u16* __restrict__ SCb,
                        const float* __restrict__ stats,
                        const float* __restrict__ g2, const float* __restrict__ b2,
                        const float* __restrict__ gsc, const float* __restrict__ bsc,
                        float* __restrict__ out) {
  long i4 = (long)blockIdx.x * 256 + threadIdx.x;
  if (i4 >= (long)NS * 32) return;
  int ch0 = ((int)i4 & 31) * 4;
  u16x4 y = *reinterpret_cast<const u16x4*>(Y2 + i4 * 4);
  u16x4 s = *reinterpret_cast<const u16x4*>(SCb + i4 * 4);
  f32x4 o;
  #pragma unroll
  for (int e = 0; e < 4; ++e) {
    int ch = ch0 + e;
    float m2 = stats[512 + ch] * (1.f / NS);
    float v2 = stats[640 + ch] * (1.f / NS) - m2 * m2;
    float a2 = g2[ch] * rsqrtf(v2 + EPSV);
    float msc = stats[256 + ch] * (1.f / NS);
    float vsc = stats[384 + ch] * (1.f / NS) - msc * msc;
    float asc = gsc[ch] * rsqrtf(vsc + EPSV);
    float val = bf2f(y[e]) * a2 + (b2[ch] - m2 * a2)
              + bf2f(s[e]) * asc + (bsc[ch] - msc * asc);
    o[e] = val > 0.f ? val : 0.f;
  }
  *reinterpret_cast<f32x4*>(out + i4 * 4) = o;
}

extern "C" void kernel_launch(void* const* d_in, const int* in_sizes, int n_in,
                              void* d_out, int out_size, void* d_ws, size_t ws_size,
                              hipStream_t stream) {
  const float* feats = (const float*)d_in[0];
  const int* in_idx  = (const int*)d_in[1];
  const int* out_idx = (const int*)d_in[2];
  const float* W1  = (const float*)d_in[3];
  const float* g1  = (const float*)d_in[4];
  const float* b1  = (const float*)d_in[5];
  const float* W2  = (const float*)d_in[6];
  const float* g2  = (const float*)d_in[7];
  const float* b2  = (const float*)d_in[8];
  const float* Wsc = (const float*)d_in[9];
  const float* gsc = (const float*)d_in[10];
  const float* bsc = (const float*)d_in[11];

  char* ws = (char*)d_ws;
  size_t off = 0;
  auto alloc = [&](size_t bytes) {
    void* p = ws + off; off += (bytes + 255) & ~(size_t)255; return p;
  };
  float* stats = (float*)alloc(768 * 4);                       // [s1,q1,ssc,qsc,s2,q2] x128
  u16* Xbf  = (u16*)alloc((size_t)(NS + 1) * 64 * 2);
  u16* SCbf = (u16*)alloc((size_t)NS * 128 * 2);
  u16* Hbf  = (u16*)alloc((size_t)(NS + 1) * 128 * 2);
  u16* Y2bf = (u16*)alloc((size_t)NS * 128 * 2);
  u16* Wp1  = (u16*)alloc((size_t)NK * 64 * 128 * 2);
  u16* Wp2  = (u16*)alloc((size_t)NK * 128 * 128 * 2);
  u16* Wpsc = (u16*)alloc((size_t)64 * 128 * 2);
  u16* Y1bf = (u16*)d_out;  // park y1 (bf16, 51.2MB) in d_out; overwritten by k_final

  hipLaunchKernelGGL(k_prep_x, dim3(50001), dim3(256), 0, stream, feats, Xbf, stats);
  hipLaunchKernelGGL(k_pack_w, dim3(2624), dim3(256), 0, stream, W1, W2, Wsc, Wp1, Wp2, Wpsc);
  hipLaunchKernelGGL((k_spconv<64, true>), dim3(3125), dim3(256), 0, stream,
                     Xbf, Wp1, Wpsc, in_idx, out_idx, Y1bf, SCbf);
  hipLaunchKernelGGL((k_stats<true>), dim3(64), dim3(256), 0, stream,
                     Y1bf, SCbf, stats, stats + 256);
  hipLaunchKernelGGL(k_bnrelu, dim3(12501), dim3(256), 0, stream, Y1bf, stats, g1, b1, Hbf);
  hipLaunchKernelGGL((k_spconv<128, false>), dim3(3125), dim3(256), 0, stream,
                     Hbf, Wp2, nullptr, in_idx, out_idx, Y2bf, nullptr);
  hipLaunchKernelGGL((k_stats<false>), dim3(64), dim3(256), 0, stream,
                     Y2bf, nullptr, stats + 512, nullptr);
  hipLaunchKernelGGL(k_final, dim3(25000), dim3(256), 0, stream,
                     Y2bf, SCbf, stats, g2, b2, gsc, bsc, (float*)d_out);
}

// Round 2
// 1510.408 us; speedup vs baseline: 1.6983x; 1.6983x over previous
//
#include <hip/hip_runtime.h>

#define NS 200000
#define NK 27
#define NBLK 782   // ceil(NS/256)
#define EPSV 1e-5f

typedef __bf16 bf16x8 __attribute__((ext_vector_type(8)));
typedef float f32x4 __attribute__((ext_vector_type(4)));
typedef unsigned short u16;
typedef u16 u16x8 __attribute__((ext_vector_type(8)));
typedef u16 u16x4 __attribute__((ext_vector_type(4)));

__device__ __forceinline__ u16 f2bf(float f) {
  union { float f; unsigned u; } v; v.f = f;
  unsigned r = v.u + 0x7fffu + ((v.u >> 16) & 1u);
  return (u16)(r >> 16);
}
__device__ __forceinline__ float bf2f(u16 u) {
  union { unsigned u; float f; } v; v.u = ((unsigned)u) << 16;
  return v.f;
}

// ---- prep: zero stats, feats f32 -> bf16 with zero row at N ----
__global__ void k_prep_x(const float* __restrict__ feats, u16* __restrict__ Xbf,
                         float* __restrict__ stats) {
  long i = (long)blockIdx.x * 256 + threadIdx.x;
  if (i < 768) stats[i] = 0.f;
  const long total = (long)(NS + 1) * 64;
  if (i < total) {
    long row = i >> 6;
    Xbf[i] = (row < NS) ? f2bf(feats[i]) : (u16)0;
  }
}

// ---- pack W [K][C][128] f32 -> MFMA-B-fragment-ordered bf16 ----
// packed f = ((k*S+s)*8+cf)*512 + r*32 + q*8 + j  <->  W[k][s*32+q*8+j][cf*16+r]
__global__ void k_pack_w(const float* __restrict__ W1, const float* __restrict__ W2,
                         const float* __restrict__ Wsc, u16* __restrict__ Wp1,
                         u16* __restrict__ Wp2, u16* __restrict__ Wpsc) {
  int i = blockIdx.x * 256 + threadIdx.x;
  const int n1 = NK * 64 * 128, n2 = NK * 128 * 128, n3 = 64 * 128;
  const float* src; u16* dst; int f, S, C;
  if (i < n1)            { src = W1;  dst = Wp1;  f = i;            S = 2; C = 64; }
  else if (i < n1 + n2)  { src = W2;  dst = Wp2;  f = i - n1;       S = 4; C = 128; }
  else if (i < n1 + n2 + n3) { src = Wsc; dst = Wpsc; f = i - n1 - n2; S = 2; C = 64; }
  else return;
  int j = f & 7, q = (f >> 3) & 3, r = (f >> 5) & 15, cf = (f >> 9) & 7;
  int rest = f >> 12;
  int s = rest % S, k = rest / S;
  int kk = s * 32 + q * 8 + j;
  dst[f] = f2bf(src[(k * C + kk) * 128 + cf * 16 + r]);
}

// ---- gather-GEMM sparse conv: 256 rows/block, 8 waves, wave tile 64x64 ----
// Register-prefetch 2-phase: issue gathers for k+1 before computing k.
template <int C, bool FUSE_SC>
__global__ __launch_bounds__(512) void k_spconv(
    const u16* __restrict__ X, const u16* __restrict__ Wp, const u16* __restrict__ Wpsc,
    const int* __restrict__ in_idx, const int* __restrict__ out_idx,
    u16* __restrict__ Ybf, u16* __restrict__ SCbf, float* __restrict__ partial) {
  constexpr int S = C / 32;        // K-slices of 32
  constexpr int CPR = C / 8;       // 16B chunks per row
  constexpr int LG = (C == 64) ? 3 : 4;
  constexpr int NST = CPR / 2;     // staged chunks per thread (512 thr, 256 rows)
  constexpr int PCOLS = FUSE_SC ? 512 : 256;
  __shared__ alignas(16) u16 Xs[256 * C];          // 32KB / 64KB
  float* red = reinterpret_cast<float*>(Xs);       // 4KB overlay, used under barriers

  const int t = threadIdx.x;
  const int w = t >> 6, l = t & 63;
  const int lr = l & 15, lh = l >> 4;
  const int wm = w >> 1, wn = w & 1;
  const int base = blockIdx.x * 256;
  const int laneoff = lr * 32 + lh * 8;

  bf16x8 st[NST];

  auto issue = [&](int k) {
    #pragma unroll
    for (int it = 0; it < NST; ++it) {
      int c = it * 512 + t;
      int row = c >> LG;
      int c8l = c & (CPR - 1);
      int c8 = (c8l & ~7) | ((c8l ^ row) & 7);   // pre-swizzled source chunk
      int srcr = NS;
      if (base + row < NS) {
        long gi = (long)k * NS + base + row;
        int oi = out_idx[gi];
        srcr = (oi != NS) ? in_idx[gi] : NS;
      }
      st[it] = *reinterpret_cast<const bf16x8*>(X + (long)srcr * C + c8 * 8);
    }
  };

  auto compute = [&](const u16* Wbase, int kidx, f32x4 (&ac)[4][4]) {
    #pragma unroll
    for (int s = 0; s < S; ++s) {
      bf16x8 a[4];
      #pragma unroll
      for (int m = 0; m < 4; ++m) {
        int row = wm * 64 + m * 16 + lr;
        int ch = s * 4 + lh;
        int lc = (ch & ~7) | ((ch ^ row) & 7);
        a[m] = *reinterpret_cast<const bf16x8*>(Xs + (row * CPR + lc) * 8);
      }
      const u16* wb = Wbase + ((long)(kidx * S + s) * 8 + wn * 4) * 512 + laneoff;
      #pragma unroll
      for (int nf = 0; nf < 4; ++nf) {
        bf16x8 b = *reinterpret_cast<const bf16x8*>(wb + (long)nf * 512);
        #pragma unroll
        for (int m = 0; m < 4; ++m)
          ac[m][nf] = __builtin_amdgcn_mfma_f32_16x16x32_bf16(a[m], b, ac[m][nf], 0, 0, 0);
      }
    }
  };

  // stores + fused per-block stats partials (poff = column offset in partial row)
  auto emit = [&](f32x4 (&ac)[4][4], u16* __restrict__ Y, int poff) {
    #pragma unroll
    for (int m = 0; m < 4; ++m)
      #pragma unroll
      for (int nf = 0; nf < 4; ++nf) {
        int ch = wn * 64 + nf * 16 + lr;
        #pragma unroll
        for (int r = 0; r < 4; ++r) {
          long row = base + wm * 64 + m * 16 + lh * 4 + r;
          if (row < NS) Y[row * 128 + ch] = f2bf(ac[m][nf][r]);
        }
      }
    __syncthreads();  // all Xs reads done before red overlay writes
    #pragma unroll
    for (int nf = 0; nf < 4; ++nf) {
      float s = 0.f, q = 0.f;
      #pragma unroll
      for (int m = 0; m < 4; ++m)
        #pragma unroll
        for (int r = 0; r < 4; ++r) { float v = ac[m][nf][r]; s += v; q += v * v; }
      s += __shfl_xor(s, 16); s += __shfl_xor(s, 32);
      q += __shfl_xor(q, 16); q += __shfl_xor(q, 32);
      if (lh == 0) {
        int ch = wn * 64 + nf * 16 + lr;
        red[wm * 256 + ch] = s;
        red[wm * 256 + 128 + ch] = q;
      }
    }
    __syncthreads();
    if (t < 256)
      partial[(long)blockIdx.x * PCOLS + poff + t] =
          red[t] + red[256 + t] + red[512 + t] + red[768 + t];
    __syncthreads();  // red reads done before Xs reuse
  };

  f32x4 acc[4][4];
  #pragma unroll
  for (int m = 0; m < 4; ++m)
    #pragma unroll
    for (int nf = 0; nf < 4; ++nf) acc[m][nf] = (f32x4){0.f, 0.f, 0.f, 0.f};

  if constexpr (FUSE_SC) {
    // shortcut phase: identity-stage own rows, GEMM with Wsc
    #pragma unroll
    for (int it = 0; it < NST; ++it) {
      int c = it * 512 + t;
      int row = c >> LG;
      int c8l = c & (CPR - 1);
      int c8 = (c8l & ~7) | ((c8l ^ row) & 7);
      int srcr = (base + row < NS) ? base + row : NS;
      *reinterpret_cast<bf16x8*>(Xs + c * 8) =
          *reinterpret_cast<const bf16x8*>(X + (long)srcr * C + c8 * 8);
    }
    __syncthreads();
    f32x4 asc[4][4];
    #pragma unroll
    for (int m = 0; m < 4; ++m)
      #pragma unroll
      for (int nf = 0; nf < 4; ++nf) asc[m][nf] = (f32x4){0.f, 0.f, 0.f, 0.f};
    compute(Wpsc, 0, asc);
    emit(asc, SCbf, 256);
  }

  issue(0);
  for (int k = 0;;) {
    #pragma unroll
    for (int it = 0; it < NST; ++it)
      *reinterpret_cast<bf16x8*>(Xs + (it * 512 + t) * 8) = st[it];
    __syncthreads();
    if (k + 1 < NK) issue(k + 1);
    compute(Wp, k, acc);
    if (++k == NK) break;
    __syncthreads();
  }
  emit(acc, Ybf, 0);
}

// ---- deterministic partial reduce: out[col] = sum over NBLK rows ----
__global__ void k_reduce(const float* __restrict__ part, float* __restrict__ out,
                         int ncols) {
  int col = blockIdx.x * 256 + threadIdx.x;
  float s0 = 0.f, s1 = 0.f;
  int r = 0;
  for (; r + 1 < NBLK; r += 2) {
    s0 += part[(long)r * ncols + col];
    s1 += part[(long)(r + 1) * ncols + col];
  }
  if (r < NBLK) s0 += part[(long)r * ncols + col];
  out[col] = s0 + s1;
}

// ---- h = relu(bn1(y1)) -> bf16 (+ zero dummy row N) ----
__global__ void k_bnrelu(const u16* __restrict__ Y1, const float* __restrict__ stats,
                         const float* __restrict__ g, const float* __restrict__ b,
                         u16* __restrict__ H) {
  long i8 = (long)blockIdx.x * 256 + threadIdx.x;
  const long tot = (long)(NS + 1) * 16;
  if (i8 >= tot) return;
  long row = i8 >> 4;
  u16x8 o;
  if (row < NS) {
    int ch0 = ((int)i8 & 15) * 8;
    u16x8 y = *reinterpret_cast<const u16x8*>(Y1 + i8 * 8);
    #pragma unroll
    for (int e = 0; e < 8; ++e) {
      int ch = ch0 + e;
      float m = stats[ch] * (1.f / NS);
      float var = stats[128 + ch] * (1.f / NS) - m * m;
      float a = g[ch] * rsqrtf(var + EPSV);
      float bb = b[ch] - m * a;
      float h = bf2f(y[e]) * a + bb;
      o[e] = f2bf(h > 0.f ? h : 0.f);
    }
  } else {
    #pragma unroll
    for (int e = 0; e < 8; ++e) o[e] = (u16)0;
  }
  *reinterpret_cast<u16x8*>(H + i8 * 8) = o;
}

// ---- out = relu(bn2(y2) + bnsc(sc)) f32 ----
__global__ void k_final(const u16* __restrict__ Y2, const u16* __restrict__ SCb,
                        const float* __restrict__ stats,
                        const float* __restrict__ g2, const float* __restrict__ b2,
                        const float* __restrict__ gsc, const float* __restrict__ bsc,
                        float* __restrict__ out) {
  long i4 = (long)blockIdx.x * 256 + threadIdx.x;
  if (i4 >= (long)NS * 32) return;
  int ch0 = ((int)i4 & 31) * 4;
  u16x4 y = *reinterpret_cast<const u16x4*>(Y2 + i4 * 4);
  u16x4 s = *reinterpret_cast<const u16x4*>(SCb + i4 * 4);
  f32x4 o;
  #pragma unroll
  for (int e = 0; e < 4; ++e) {
    int ch = ch0 + e;
    float m2 = stats[512 + ch] * (1.f / NS);
    float v2 = stats[640 + ch] * (1.f / NS) - m2 * m2;
    float a2 = g2[ch] * rsqrtf(v2 + EPSV);
    float msc = stats[256 + ch] * (1.f / NS);
    float vsc = stats[384 + ch] * (1.f / NS) - msc * msc;
    float asc = gsc[ch] * rsqrtf(vsc + EPSV);
    float val = bf2f(y[e]) * a2 + (b2[ch] - m2 * a2)
              + bf2f(s[e]) * asc + (bsc[ch] - msc * asc);
    o[e] = val > 0.f ? val : 0.f;
  }
  *reinterpret_cast<f32x4*>(out + i4 * 4) = o;
}

extern "C" void kernel_launch(void* const* d_in, const int* in_sizes, int n_in,
                              void* d_out, int out_size, void* d_ws, size_t ws_size,
                              hipStream_t stream) {
  const float* feats = (const float*)d_in[0];
  const int* in_idx  = (const int*)d_in[1];
  const int* out_idx = (const int*)d_in[2];
  const float* W1  = (const float*)d_in[3];
  const float* g1  = (const float*)d_in[4];
  const float* b1  = (const float*)d_in[5];
  const float* W2  = (const float*)d_in[6];
  const float* g2  = (const float*)d_in[7];
  const float* b2  = (const float*)d_in[8];
  const float* Wsc = (const float*)d_in[9];
  const float* gsc = (const float*)d_in[10];
  const float* bsc = (const float*)d_in[11];

  char* ws = (char*)d_ws;
  size_t off = 0;
  auto alloc = [&](size_t bytes) {
    void* p = ws + off; off += (bytes + 255) & ~(size_t)255; return p;
  };
  float* stats = (float*)alloc(768 * 4);               // [s1,q1,ssc,qsc,s2,q2] x128
  u16* Xbf  = (u16*)alloc((size_t)(NS + 1) * 64 * 2);
  u16* SCbf = (u16*)alloc((size_t)NS * 128 * 2);
  u16* Hbf  = (u16*)alloc((size_t)(NS + 1) * 128 * 2);
  u16* Y2bf = (u16*)alloc((size_t)NS * 128 * 2);
  u16* Wp1  = (u16*)alloc((size_t)NK * 64 * 128 * 2);
  u16* Wp2  = (u16*)alloc((size_t)NK * 128 * 128 * 2);
  u16* Wpsc = (u16*)alloc((size_t)64 * 128 * 2);
  u16* Y1bf = (u16*)d_out;              // park y1 bf16 in d_out; k_final overwrites
  // partials alias dead regions (timeline-safe):
  float* part1 = (float*)Y2bf;          // consumed by reduce1 before conv2 writes Y2
  float* part2 = (float*)Xbf;           // Xbf dead after conv1

  hipLaunchKernelGGL(k_prep_x, dim3(50001), dim3(256), 0, stream, feats, Xbf, stats);
  hipLaunchKernelGGL(k_pack_w, dim3(2624), dim3(256), 0, stream, W1, W2, Wsc, Wp1, Wp2, Wpsc);
  hipLaunchKernelGGL((k_spconv<64, true>), dim3(NBLK), dim3(512), 0, stream,
                     Xbf, Wp1, Wpsc, in_idx, out_idx, Y1bf, SCbf, part1);
  hipLaunchKernelGGL(k_reduce, dim3(2), dim3(256), 0, stream, part1, stats, 512);
  hipLaunchKernelGGL(k_bnrelu, dim3(12501), dim3(256), 0, stream, Y1bf, stats, g1, b1, Hbf);
  hipLaunchKernelGGL((k_spconv<128, false>), dim3(NBLK), dim3(512), 0, stream,
                     Hbf, Wp2, nullptr, in_idx, out_idx, Y2bf, nullptr, part2);
  hipLaunchKernelGGL(k_reduce, dim3(1), dim3(256), 0, stream, part2, stats + 512, 256);
  hipLaunchKernelGGL(k_final, dim3(25000), dim3(256), 0, stream,
                     Y2bf, SCbf, stats, g2, b2, gsc, bsc, (float*)d_out);
}

// Round 3
// 996.067 us; speedup vs baseline: 2.5753x; 1.5164x over previous
//
#include <hip/hip_runtime.h>

#define NS 200000
#define NK 27
#define NB2 1563   // ceil(NS/128)
#define EPSV 1e-5f

typedef __bf16 bf16x8 __attribute__((ext_vector_type(8)));
typedef float f32x4 __attribute__((ext_vector_type(4)));
typedef unsigned short u16;
typedef u16 u16x8 __attribute__((ext_vector_type(8)));
typedef u16 u16x4 __attribute__((ext_vector_type(4)));

__device__ __forceinline__ u16 f2bf(float f) {
  union { float f; unsigned u; } v; v.f = f;
  unsigned r = v.u + 0x7fffu + ((v.u >> 16) & 1u);
  return (u16)(r >> 16);
}
__device__ __forceinline__ float bf2f(u16 u) {
  union { unsigned u; float f; } v; v.u = ((unsigned)u) << 16;
  return v.f;
}

// ---- prep: zero stats, feats f32 -> bf16 with zero row at N ----
__global__ void k_prep_x(const float* __restrict__ feats, u16* __restrict__ Xbf,
                         float* __restrict__ stats) {
  long i = (long)blockIdx.x * 256 + threadIdx.x;
  if (i < 768) stats[i] = 0.f;
  const long total = (long)(NS + 1) * 64;
  if (i < total) {
    long row = i >> 6;
    Xbf[i] = (row < NS) ? f2bf(feats[i]) : (u16)0;
  }
}

// ---- pack W [K][C][128] f32 -> MFMA-B-fragment-ordered bf16 ----
// packed f = ((k*S+s)*8+cf)*512 + r*32 + q*8 + j  <->  W[k][s*32+q*8+j][cf*16+r]
__global__ void k_pack_w(const float* __restrict__ W1, const float* __restrict__ W2,
                         const float* __restrict__ Wsc, u16* __restrict__ Wp1,
                         u16* __restrict__ Wp2, u16* __restrict__ Wpsc) {
  int i = blockIdx.x * 256 + threadIdx.x;
  const int n1 = NK * 64 * 128, n2 = NK * 128 * 128, n3 = 64 * 128;
  const float* src; u16* dst; int f, S, C;
  if (i < n1)            { src = W1;  dst = Wp1;  f = i;            S = 2; C = 64; }
  else if (i < n1 + n2)  { src = W2;  dst = Wp2;  f = i - n1;       S = 4; C = 128; }
  else if (i < n1 + n2 + n3) { src = Wsc; dst = Wpsc; f = i - n1 - n2; S = 2; C = 64; }
  else return;
  int j = f & 7, q = (f >> 3) & 3, r = (f >> 5) & 15, cf = (f >> 9) & 7;
  int rest = f >> 12;
  int s = rest % S, k = rest / S;
  int kk = s * 32 + q * 8 + j;
  dst[f] = f2bf(src[(k * C + kk) * 128 + cf * 16 + r]);
}

// ---- barrier-free direct-gather conv ----
// 4 waves/block, each wave owns a 32-row x 128-col output tile.
// A-fragments gathered per-lane straight from global (no LDS, no barriers);
// idx prefetched 2 k-steps ahead, gathers 1 step ahead; full unroll ->
// compiler emits counted vmcnt pipelining across k.
template <int C, bool FUSE_SC>
__global__ __launch_bounds__(256, 2) void k_conv(
    const u16* __restrict__ X, const u16* __restrict__ Wp, const u16* __restrict__ Wpsc,
    const int* __restrict__ in_idx, const int* __restrict__ out_idx,
    u16* __restrict__ Y, u16* __restrict__ SCb, float* __restrict__ partial) {
  constexpr int S = C / 32;
  constexpr int PC = FUSE_SC ? 512 : 256;
  __shared__ float red[1024];
  const int t = threadIdx.x, w = t >> 6, l = t & 63;
  const int lr = l & 15, lh = l >> 4;
  const int rowbase = blockIdx.x * 128 + w * 32;
  const int laneoff = lr * 32 + lh * 8;

  int rr[2]; long rc[2]; bool ok[2];
  #pragma unroll
  for (int m = 0; m < 2; ++m) {
    rr[m] = rowbase + m * 16 + lr;
    ok[m] = rr[m] < NS;
    rc[m] = ok[m] ? rr[m] : 0;   // safe idx address for OOB lanes
  }

  auto emit = [&](f32x4 (&ac)[2][8], u16* __restrict__ Yp, int poff) {
    #pragma unroll
    for (int m = 0; m < 2; ++m)
      #pragma unroll
      for (int cf = 0; cf < 8; ++cf) {
        int ch = cf * 16 + lr;
        #pragma unroll
        for (int r = 0; r < 4; ++r) {
          long row = rowbase + m * 16 + lh * 4 + r;
          if (row < NS) Yp[row * 128 + ch] = f2bf(ac[m][cf][r]);
        }
      }
    #pragma unroll
    for (int cf = 0; cf < 8; ++cf) {
      float s = 0.f, q = 0.f;
      #pragma unroll
      for (int m = 0; m < 2; ++m)
        #pragma unroll
        for (int r = 0; r < 4; ++r) { float v = ac[m][cf][r]; s += v; q += v * v; }
      s += __shfl_xor(s, 16); s += __shfl_xor(s, 32);
      q += __shfl_xor(q, 16); q += __shfl_xor(q, 32);
      if (lh == 0) {
        red[w * 256 + cf * 16 + lr] = s;
        red[w * 256 + 128 + cf * 16 + lr] = q;
      }
    }
    __syncthreads();
    if (t < 256)
      partial[(long)blockIdx.x * PC + poff + t] =
          red[t] + red[256 + t] + red[512 + t] + red[768 + t];
    __syncthreads();
  };

  auto loadidx = [&](int k, int (&dst)[2]) {
    #pragma unroll
    for (int m = 0; m < 2; ++m) {
      long gi = (long)k * NS + rc[m];
      int oi = out_idx[gi];
      int ii = in_idx[gi];
      dst[m] = (ok[m] && oi != NS) ? ii : NS;  // loads independent; select cheap
    }
  };
  auto gather = [&](const int (&src)[2], bf16x8 (&a)[2][S]) {
    #pragma unroll
    for (int m = 0; m < 2; ++m)
      #pragma unroll
      for (int s = 0; s < S; ++s)
        a[m][s] = *reinterpret_cast<const bf16x8*>(X + (long)src[m] * C + (s * 4 + lh) * 8);
  };

  if constexpr (FUSE_SC) {
    // shortcut: identity gather of own rows, GEMM with Wsc
    bf16x8 ai[2][S];
    #pragma unroll
    for (int m = 0; m < 2; ++m)
      #pragma unroll
      for (int s = 0; s < S; ++s) {
        long srcr = ok[m] ? rr[m] : NS;
        ai[m][s] = *reinterpret_cast<const bf16x8*>(X + srcr * C + (s * 4 + lh) * 8);
      }
    f32x4 asc[2][8];
    #pragma unroll
    for (int m = 0; m < 2; ++m)
      #pragma unroll
      for (int cf = 0; cf < 8; ++cf) asc[m][cf] = (f32x4){0.f, 0.f, 0.f, 0.f};
    #pragma unroll
    for (int s = 0; s < S; ++s)
      #pragma unroll
      for (int cf = 0; cf < 8; ++cf) {
        bf16x8 b = *reinterpret_cast<const bf16x8*>(Wpsc + (s * 8 + cf) * 512 + laneoff);
        #pragma unroll
        for (int m = 0; m < 2; ++m)
          asc[m][cf] = __builtin_amdgcn_mfma_f32_16x16x32_bf16(ai[m][s], b, asc[m][cf], 0, 0, 0);
      }
    emit(asc, SCb, 256);
  }

  f32x4 acc[2][8];
  #pragma unroll
  for (int m = 0; m < 2; ++m)
    #pragma unroll
    for (int cf = 0; cf < 8; ++cf) acc[m][cf] = (f32x4){0.f, 0.f, 0.f, 0.f};

  int sv[2][2];
  bf16x8 av[2][2][S];
  loadidx(0, sv[0]);
  gather(sv[0], av[0]);
  loadidx(1, sv[1]);

  #pragma unroll
  for (int k = 0; k < NK; ++k) {
    const int cur = k & 1, nxt = cur ^ 1;
    if (k + 2 < NK) loadidx(k + 2, sv[cur]);   // idx for k+2 (slot freed last iter)
    if (k + 1 < NK) gather(sv[nxt], av[nxt]);  // A-frags for k+1
    const u16* wb = Wp + (long)k * (S * 8 * 512) + laneoff;
    #pragma unroll
    for (int s = 0; s < S; ++s)
      #pragma unroll
      for (int cf = 0; cf < 8; ++cf) {
        bf16x8 b = *reinterpret_cast<const bf16x8*>(wb + (s * 8 + cf) * 512);
        acc[0][cf] = __builtin_amdgcn_mfma_f32_16x16x32_bf16(av[cur][0][s], b, acc[0][cf], 0, 0, 0);
        acc[1][cf] = __builtin_amdgcn_mfma_f32_16x16x32_bf16(av[cur][1][s], b, acc[1][cf], 0, 0, 0);
      }
  }
  emit(acc, Y, 0);
}

// ---- deterministic 2-stage partial reduce ----
__global__ void k_red1(const float* __restrict__ part, float* __restrict__ tmp,
                       int pc, int nrows) {
  int c = blockIdx.x * 256 + threadIdx.x;
  float s = 0.f;
  for (int r = blockIdx.y; r < nrows; r += 32) s += part[(long)r * pc + c];
  tmp[(long)blockIdx.y * pc + c] = s;
}
__global__ void k_red2(const float* __restrict__ tmp, float* __restrict__ out, int pc) {
  int c = blockIdx.x * 256 + threadIdx.x;
  float s = 0.f;
  #pragma unroll
  for (int r = 0; r < 32; ++r) s += tmp[(long)r * pc + c];
  out[c] = s;
}

// ---- h = relu(bn1(y1)) -> bf16 (+ zero dummy row N) ----
__global__ void k_bnrelu(const u16* __restrict__ Y1, const float* __restrict__ stats,
                         const float* __restrict__ g, const float* __restrict__ b,
                         u16* __restrict__ H) {
  long i8 = (long)blockIdx.x * 256 + threadIdx.x;
  const long tot = (long)(NS + 1) * 16;
  if (i8 >= tot) return;
  long row = i8 >> 4;
  u16x8 o;
  if (row < NS) {
    int ch0 = ((int)i8 & 15) * 8;
    u16x8 y = *reinterpret_cast<const u16x8*>(Y1 + i8 * 8);
    #pragma unroll
    for (int e = 0; e < 8; ++e) {
      int ch = ch0 + e;
      float m = stats[ch] * (1.f / NS);
      float var = stats[128 + ch] * (1.f / NS) - m * m;
      float a = g[ch] * rsqrtf(var + EPSV);
      float bb = b[ch] - m * a;
      float h = bf2f(y[e]) * a + bb;
      o[e] = f2bf(h > 0.f ? h : 0.f);
    }
  } else {
    #pragma unroll
    for (int e = 0; e < 8; ++e) o[e] = (u16)0;
  }
  *reinterpret_cast<u16x8*>(H + i8 * 8) = o;
}

// ---- out = relu(bn2(y2) + bnsc(sc)) f32 ----
__global__ void k_final(const u16* __restrict__ Y2, const u16* __restrict__ SCb,
                        const float* __restrict__ stats,
                        const float* __restrict__ g2, const float* __restrict__ b2,
                        const float* __restrict__ gsc, const float* __restrict__ bsc,
                        float* __restrict__ out) {
  long i4 = (long)blockIdx.x * 256 + threadIdx.x;
  if (i4 >= (long)NS * 32) return;
  int ch0 = ((int)i4 & 31) * 4;
  u16x4 y = *reinterpret_cast<const u16x4*>(Y2 + i4 * 4);
  u16x4 s = *reinterpret_cast<const u16x4*>(SCb + i4 * 4);
  f32x4 o;
  #pragma unroll
  for (int e = 0; e < 4; ++e) {
    int ch = ch0 + e;
    float m2 = stats[512 + ch] * (1.f / NS);
    float v2 = stats[640 + ch] * (1.f / NS) - m2 * m2;
    float a2 = g2[ch] * rsqrtf(v2 + EPSV);
    float msc = stats[256 + ch] * (1.f / NS);
    float vsc = stats[384 + ch] * (1.f / NS) - msc * msc;
    float asc = gsc[ch] * rsqrtf(vsc + EPSV);
    float val = bf2f(y[e]) * a2 + (b2[ch] - m2 * a2)
              + bf2f(s[e]) * asc + (bsc[ch] - msc * asc);
    o[e] = val > 0.f ? val : 0.f;
  }
  *reinterpret_cast<f32x4*>(out + i4 * 4) = o;
}

extern "C" void kernel_launch(void* const* d_in, const int* in_sizes, int n_in,
                              void* d_out, int out_size, void* d_ws, size_t ws_size,
                              hipStream_t stream) {
  const float* feats = (const float*)d_in[0];
  const int* in_idx  = (const int*)d_in[1];
  const int* out_idx = (const int*)d_in[2];
  const float* W1  = (const float*)d_in[3];
  const float* g1  = (const float*)d_in[4];
  const float* b1  = (const float*)d_in[5];
  const float* W2  = (const float*)d_in[6];
  const float* g2  = (const float*)d_in[7];
  const float* b2  = (const float*)d_in[8];
  const float* Wsc = (const float*)d_in[9];
  const float* gsc = (const float*)d_in[10];
  const float* bsc = (const float*)d_in[11];

  char* ws = (char*)d_ws;
  size_t off = 0;
  auto alloc = [&](size_t bytes) {
    void* p = ws + off; off += (bytes + 255) & ~(size_t)255; return p;
  };
  float* stats = (float*)alloc(768 * 4);               // [s1,q1,ssc,qsc,s2,q2] x128
  float* rtmp  = (float*)alloc(32 * 512 * 4);          // reduce stage-1 output
  u16* Xbf  = (u16*)alloc((size_t)(NS + 1) * 64 * 2);
  u16* SCbf = (u16*)alloc((size_t)NS * 128 * 2);
  u16* Hbf  = (u16*)alloc((size_t)(NS + 1) * 128 * 2);
  u16* Y2bf = (u16*)alloc((size_t)NS * 128 * 2);
  u16* Wp1  = (u16*)alloc((size_t)NK * 64 * 128 * 2);
  u16* Wp2  = (u16*)alloc((size_t)NK * 128 * 128 * 2);
  u16* Wpsc = (u16*)alloc((size_t)64 * 128 * 2);
  u16* Y1bf = (u16*)d_out;              // park y1 bf16 in d_out; k_final overwrites
  float* part1 = (float*)Y2bf;          // 3.2MB, dead region until conv2
  float* part2 = (float*)Xbf;           // Xbf dead after conv1

  hipLaunchKernelGGL(k_prep_x, dim3(50001), dim3(256), 0, stream, feats, Xbf, stats);
  hipLaunchKernelGGL(k_pack_w, dim3(2624), dim3(256), 0, stream, W1, W2, Wsc, Wp1, Wp2, Wpsc);
  hipLaunchKernelGGL((k_conv<64, true>), dim3(NB2), dim3(256), 0, stream,
                     Xbf, Wp1, Wpsc, in_idx, out_idx, Y1bf, SCbf, part1);
  hipLaunchKernelGGL(k_red1, dim3(2, 32), dim3(256), 0, stream, part1, rtmp, 512, NB2);
  hipLaunchKernelGGL(k_red2, dim3(2), dim3(256), 0, stream, rtmp, stats, 512);
  hipLaunchKernelGGL(k_bnrelu, dim3(12501), dim3(256), 0, stream, Y1bf, stats, g1, b1, Hbf);
  hipLaunchKernelGGL((k_conv<128, false>), dim3(NB2), dim3(256), 0, stream,
                     Hbf, Wp2, nullptr, in_idx, out_idx, Y2bf, nullptr, part2);
  hipLaunchKernelGGL(k_red1, dim3(1, 32), dim3(256), 0, stream, part2, rtmp, 256, NB2);
  hipLaunchKernelGGL(k_red2, dim3(1), dim3(256), 0, stream, rtmp, stats + 512, 256);
  hipLaunchKernelGGL(k_final, dim3(25000), dim3(256), 0, stream,
                     Y2bf, SCbf, stats, g2, b2, gsc, bsc, (float*)d_out);
}

// Round 4
// 480.855 us; speedup vs baseline: 5.3346x; 2.0715x over previous
//
#include <hip/hip_runtime.h>

#define NS 200000
#define NK 27
#define NB2 1563   // ceil(NS/128)
#define EPSV 1e-5f

typedef __bf16 bf16x8 __attribute__((ext_vector_type(8)));
typedef float f32x4 __attribute__((ext_vector_type(4)));
typedef unsigned short u16;
typedef u16 u16x8 __attribute__((ext_vector_type(8)));
typedef u16 u16x4 __attribute__((ext_vector_type(4)));
typedef unsigned u32;

__device__ __forceinline__ u16 f2bf(float f) {
  union { float f; unsigned u; } v; v.f = f;
  unsigned r = v.u + 0x7fffu + ((v.u >> 16) & 1u);
  return (u16)(r >> 16);
}
__device__ __forceinline__ float bf2f(u16 u) {
  union { unsigned u; float f; } v; v.u = ((unsigned)u) << 16;
  return v.f;
}

// ---- prep: zero stats, feats f32 -> bf16 with zero row at N ----
__global__ void k_prep_x(const float* __restrict__ feats, u16* __restrict__ Xbf,
                         float* __restrict__ stats) {
  long i = (long)blockIdx.x * 256 + threadIdx.x;
  if (i < 768) stats[i] = 0.f;
  const long total = (long)(NS + 1) * 64;
  if (i < total) {
    long row = i >> 6;
    Xbf[i] = (row < NS) ? f2bf(feats[i]) : (u16)0;
  }
}

// ---- fused gather index: gidx = valid ? in_idx : NS ----
__global__ void k_prep_gidx(const int* __restrict__ in_idx, const int* __restrict__ out_idx,
                            int* __restrict__ gidx) {
  long i = (long)blockIdx.x * 256 + threadIdx.x;
  if (i < (long)NK * NS) gidx[i] = (out_idx[i] != NS) ? in_idx[i] : NS;
}

// ---- pack W [K][C][128] f32 -> MFMA-B-fragment-ordered bf16 ----
// packed f = ((k*S+s)*8+cf)*512 + r*32 + q*8 + j  <->  W[k][s*32+q*8+j][cf*16+r]
__global__ void k_pack_w(const float* __restrict__ W1, const float* __restrict__ W2,
                         const float* __restrict__ Wsc, u16* __restrict__ Wp1,
                         u16* __restrict__ Wp2, u16* __restrict__ Wpsc) {
  int i = blockIdx.x * 256 + threadIdx.x;
  const int n1 = NK * 64 * 128, n2 = NK * 128 * 128, n3 = 64 * 128;
  const float* src; u16* dst; int f, S, C;
  if (i < n1)            { src = W1;  dst = Wp1;  f = i;            S = 2; C = 64; }
  else if (i < n1 + n2)  { src = W2;  dst = Wp2;  f = i - n1;       S = 4; C = 128; }
  else if (i < n1 + n2 + n3) { src = Wsc; dst = Wpsc; f = i - n1 - n2; S = 2; C = 64; }
  else return;
  int j = f & 7, q = (f >> 3) & 3, r = (f >> 5) & 15, cf = (f >> 9) & 7;
  int rest = f >> 12;
  int s = rest % S, k = rest / S;
  int kk = s * 32 + q * 8 + j;
  dst[f] = f2bf(src[(k * C + kk) * 128 + cf * 16 + r]);
}

// ---- gather-GEMM conv: W staged in LDS (dbuf, global_load_lds), A gathered
// per-lane from global, counted-vmcnt raw barriers (no full drains in loop) ----
template <int C, bool FUSE_SC>
__global__ __launch_bounds__(256, (C == 64) ? 3 : 2) void k_conv(
    const u16* __restrict__ X, const u16* __restrict__ Wp, const u16* __restrict__ Wpsc,
    const int* __restrict__ gidx,
    u16* __restrict__ Y, u16* __restrict__ SCb, float* __restrict__ partial) {
  constexpr int S = C / 32;            // K-slices of 32
  constexpr int SLICE = C * 128;       // u16 elems per packed k-slice
  constexpr int NST = SLICE / 2048;    // global_load_lds issues per wave per k
  constexpr int NG = 2 * S;            // gather loads per wave per k
  constexpr int NW_STEADY = NG + 2 + NST + NG + 2;
  constexpr int PC = FUSE_SC ? 512 : 256;
  __shared__ alignas(16) u16 Wbuf[2 * SLICE];
  float* red = reinterpret_cast<float*>(&Wbuf[2 * SLICE - 2048]);  // last 4KB

  const int t = threadIdx.x, w = t >> 6, l = t & 63;
  const int lr = l & 15, lh = l >> 4;
  const int rowbase = blockIdx.x * 128 + w * 32;
  const int laneoff = lr * 32 + lh * 8;

  int rr[2]; bool ok[2]; long rc[2];
  #pragma unroll
  for (int m = 0; m < 2; ++m) {
    rr[m] = rowbase + m * 16 + lr;
    ok[m] = rr[m] < NS;
    rc[m] = ok[m] ? rr[m] : 0;
  }

  auto stage = [&](int k, int bsel) {
    #pragma unroll
    for (int i = 0; i < NST; ++i) {
      const u16* g = Wp + (long)k * SLICE + (w * NST + i) * 512 + l * 8;
      u16* d = &Wbuf[bsel * SLICE + (w * NST + i) * 512];
      __builtin_amdgcn_global_load_lds(
          (const __attribute__((address_space(1))) u32*)g,
          (__attribute__((address_space(3))) u32*)d, 16, 0, 0);
    }
  };
  auto loadidx = [&](int k, int (&dst)[2]) {
    #pragma unroll
    for (int m = 0; m < 2; ++m) {
      int v = gidx[(long)k * NS + rc[m]];
      dst[m] = ok[m] ? v : NS;
    }
  };
  auto gather = [&](const int (&src)[2], bf16x8 (&a)[2][S]) {
    #pragma unroll
    for (int m = 0; m < 2; ++m) {
      const u16* rowp = X + (long)src[m] * C + lh * 8;
      #pragma unroll
      for (int s = 0; s < S; ++s)
        a[m][s] = *reinterpret_cast<const bf16x8*>(rowp + s * 32);
    }
  };
  auto compute = [&](int bsel, const bf16x8 (&a)[2][S], f32x4 (&ac)[2][8]) {
    #pragma unroll
    for (int s = 0; s < S; ++s)
      #pragma unroll
      for (int cf = 0; cf < 8; ++cf) {
        bf16x8 b = *reinterpret_cast<const bf16x8*>(&Wbuf[bsel * SLICE + (s * 8 + cf) * 512 + laneoff]);
        ac[0][cf] = __builtin_amdgcn_mfma_f32_16x16x32_bf16(a[0][s], b, ac[0][cf], 0, 0, 0);
        ac[1][cf] = __builtin_amdgcn_mfma_f32_16x16x32_bf16(a[1][s], b, ac[1][cf], 0, 0, 0);
      }
  };
  auto emit = [&](f32x4 (&ac)[2][8], u16* __restrict__ Yp, int poff) {
    #pragma unroll
    for (int m = 0; m < 2; ++m)
      #pragma unroll
      for (int cf = 0; cf < 8; ++cf) {
        int ch = cf * 16 + lr;
        #pragma unroll
        for (int r = 0; r < 4; ++r) {
          long row = rowbase + m * 16 + lh * 4 + r;
          if (row < NS) Yp[row * 128 + ch] = f2bf(ac[m][cf][r]);
        }
      }
    __syncthreads();  // full drain; safe to overlay red on Wbuf tail
    #pragma unroll
    for (int cf = 0; cf < 8; ++cf) {
      float s = 0.f, q = 0.f;
      #pragma unroll
      for (int m = 0; m < 2; ++m)
        #pragma unroll
        for (int r = 0; r < 4; ++r) { float v = ac[m][cf][r]; s += v; q += v * v; }
      s += __shfl_xor(s, 16); s += __shfl_xor(s, 32);
      q += __shfl_xor(q, 16); q += __shfl_xor(q, 32);
      if (lh == 0) {
        red[w * 256 + cf * 16 + lr] = s;
        red[w * 256 + 128 + cf * 16 + lr] = q;
      }
    }
    __syncthreads();
    if (t < 256)
      partial[(long)blockIdx.x * PC + poff + t] =
          red[t] + red[256 + t] + red[512 + t] + red[768 + t];
    __syncthreads();
  };

  // ---- pipeline prologue (issue before SC work so latency hides under it) ----
  int sv0[2], sv1[2];
  bf16x8 av0[2][S], av1[2][S];
  loadidx(0, sv0);
  stage(0, 0);
  gather(sv0, av0);
  loadidx(1, sv1);

  if constexpr (FUSE_SC) {
    // shortcut: identity gather of own rows, B-frags direct from global (one-time)
    bf16x8 ai[2][S];
    #pragma unroll
    for (int m = 0; m < 2; ++m) {
      long srcr = ok[m] ? rr[m] : NS;
      #pragma unroll
      for (int s = 0; s < S; ++s)
        ai[m][s] = *reinterpret_cast<const bf16x8*>(X + srcr * C + lh * 8 + s * 32);
    }
    f32x4 asc[2][8];
    #pragma unroll
    for (int m = 0; m < 2; ++m)
      #pragma unroll
      for (int cf = 0; cf < 8; ++cf) asc[m][cf] = (f32x4){0.f, 0.f, 0.f, 0.f};
    #pragma unroll
    for (int s = 0; s < S; ++s)
      #pragma unroll
      for (int cf = 0; cf < 8; ++cf) {
        bf16x8 b = *reinterpret_cast<const bf16x8*>(Wpsc + (s * 8 + cf) * 512 + laneoff);
        asc[0][cf] = __builtin_amdgcn_mfma_f32_16x16x32_bf16(ai[0][s], b, asc[0][cf], 0, 0, 0);
        asc[1][cf] = __builtin_amdgcn_mfma_f32_16x16x32_bf16(ai[1][s], b, asc[1][cf], 0, 0, 0);
      }
    emit(asc, SCb, 256);  // ends with full drain -> loop-entry waits are trivially safe
  }

  f32x4 acc[2][8];
  #pragma unroll
  for (int m = 0; m < 2; ++m)
    #pragma unroll
    for (int cf = 0; cf < 8; ++cf) acc[m][cf] = (f32x4){0.f, 0.f, 0.f, 0.f};

  // ---- main loop: double-step k, k+1 (static buffer/reg parity) ----
  #pragma unroll 1
  for (int k = 0; k < 24; k += 2) {
    stage(k + 1, 1);
    gather(sv1, av1);
    loadidx(k + 2, sv0);
    asm volatile("s_waitcnt vmcnt(%0)\n\ts_barrier" :: "i"(NW_STEADY) : "memory");
    compute(0, av0, acc);
    asm volatile("s_waitcnt lgkmcnt(0)\n\ts_barrier" ::: "memory");

    stage(k + 2, 0);
    gather(sv0, av0);
    loadidx(k + 3, sv1);
    asm volatile("s_waitcnt vmcnt(%0)\n\ts_barrier" :: "i"(NW_STEADY) : "memory");
    compute(1, av1, acc);
    asm volatile("s_waitcnt lgkmcnt(0)\n\ts_barrier" ::: "memory");
  }
  // ---- peeled k=24,25,26 with exact tail counts ----
  stage(25, 1);
  gather(sv1, av1);
  loadidx(26, sv0);
  asm volatile("s_waitcnt vmcnt(%0)\n\ts_barrier" :: "i"(NW_STEADY) : "memory");
  compute(0, av0, acc);
  asm volatile("s_waitcnt lgkmcnt(0)\n\ts_barrier" ::: "memory");

  stage(26, 0);
  gather(sv0, av0);
  asm volatile("s_waitcnt vmcnt(%0)\n\ts_barrier" :: "i"(NW_STEADY - 2) : "memory");
  compute(1, av1, acc);
  asm volatile("s_waitcnt lgkmcnt(0)\n\ts_barrier" ::: "memory");

  asm volatile("s_waitcnt vmcnt(%0)\n\ts_barrier" :: "i"(NG) : "memory");
  compute(0, av0, acc);

  emit(acc, Y, 0);
}

// ---- deterministic 2-stage partial reduce ----
__global__ void k_red1(const float* __restrict__ part, float* __restrict__ tmp,
                       int pc, int nrows) {
  int c = blockIdx.x * 256 + threadIdx.x;
  float s = 0.f;
  for (int r = blockIdx.y; r < nrows; r += 32) s += part[(long)r * pc + c];
  tmp[(long)blockIdx.y * pc + c] = s;
}
__global__ void k_red2(const float* __restrict__ tmp, float* __restrict__ out, int pc) {
  int c = blockIdx.x * 256 + threadIdx.x;
  float s = 0.f;
  #pragma unroll
  for (int r = 0; r < 32; ++r) s += tmp[(long)r * pc + c];
  out[c] = s;
}

// ---- h = relu(bn1(y1)) -> bf16 (+ zero dummy row N) ----
__global__ void k_bnrelu(const u16* __restrict__ Y1, const float* __restrict__ stats,
                         const float* __restrict__ g, const float* __restrict__ b,
                         u16* __restrict__ H) {
  long i8 = (long)blockIdx.x * 256 + threadIdx.x;
  const long tot = (long)(NS + 1) * 16;
  if (i8 >= tot) return;
  long row = i8 >> 4;
  u16x8 o;
  if (row < NS) {
    int ch0 = ((int)i8 & 15) * 8;
    u16x8 y = *reinterpret_cast<const u16x8*>(Y1 + i8 * 8);
    #pragma unroll
    for (int e = 0; e < 8; ++e) {
      int ch = ch0 + e;
      float m = stats[ch] * (1.f / NS);
      float var = stats[128 + ch] * (1.f / NS) - m * m;
      float a = g[ch] * rsqrtf(var + EPSV);
      float bb = b[ch] - m * a;
      float h = bf2f(y[e]) * a + bb;
      o[e] = f2bf(h > 0.f ? h : 0.f);
    }
  } else {
    #pragma unroll
    for (int e = 0; e < 8; ++e) o[e] = (u16)0;
  }
  *reinterpret_cast<u16x8*>(H + i8 * 8) = o;
}

// ---- out = relu(bn2(y2) + bnsc(sc)) f32 ----
__global__ void k_final(const u16* __restrict__ Y2, const u16* __restrict__ SCb,
                        const float* __restrict__ stats,
                        const float* __restrict__ g2, const float* __restrict__ b2,
                        const float* __restrict__ gsc, const float* __restrict__ bsc,
                        float* __restrict__ out) {
  long i4 = (long)blockIdx.x * 256 + threadIdx.x;
  if (i4 >= (long)NS * 32) return;
  int ch0 = ((int)i4 & 31) * 4;
  u16x4 y = *reinterpret_cast<const u16x4*>(Y2 + i4 * 4);
  u16x4 s = *reinterpret_cast<const u16x4*>(SCb + i4 * 4);
  f32x4 o;
  #pragma unroll
  for (int e = 0; e < 4; ++e) {
    int ch = ch0 + e;
    float m2 = stats[512 + ch] * (1.f / NS);
    float v2 = stats[640 + ch] * (1.f / NS) - m2 * m2;
    float a2 = g2[ch] * rsqrtf(v2 + EPSV);
    float msc = stats[256 + ch] * (1.f / NS);
    float vsc = stats[384 + ch] * (1.f / NS) - msc * msc;
    float asc = gsc[ch] * rsqrtf(vsc + EPSV);
    float val = bf2f(y[e]) * a2 + (b2[ch] - m2 * a2)
              + bf2f(s[e]) * asc + (bsc[ch] - msc * asc);
    o[e] = val > 0.f ? val : 0.f;
  }
  *reinterpret_cast<f32x4*>(out + i4 * 4) = o;
}

extern "C" void kernel_launch(void* const* d_in, const int* in_sizes, int n_in,
                              void* d_out, int out_size, void* d_ws, size_t ws_size,
                              hipStream_t stream) {
  const float* feats = (const float*)d_in[0];
  const int* in_idx  = (const int*)d_in[1];
  const int* out_idx = (const int*)d_in[2];
  const float* W1  = (const float*)d_in[3];
  const float* g1  = (const float*)d_in[4];
  const float* b1  = (const float*)d_in[5];
  const float* W2  = (const float*)d_in[6];
  const float* g2  = (const float*)d_in[7];
  const float* b2  = (const float*)d_in[8];
  const float* Wsc = (const float*)d_in[9];
  const float* gsc = (const float*)d_in[10];
  const float* bsc = (const float*)d_in[11];

  char* ws = (char*)d_ws;
  size_t off = 0;
  auto alloc = [&](size_t bytes) {
    void* p = ws + off; off += (bytes + 255) & ~(size_t)255; return p;
  };
  float* stats = (float*)alloc(768 * 4);               // [s1,q1,ssc,qsc,s2,q2] x128
  float* rtmp  = (float*)alloc(32 * 512 * 4);          // reduce stage-1 output
  u16* Xbf  = (u16*)alloc((size_t)(NS + 1) * 64 * 2);
  u16* SCbf = (u16*)alloc((size_t)NS * 128 * 2);
  u16* Hbf  = (u16*)alloc((size_t)(NS + 1) * 128 * 2);
  u16* Y2bf = (u16*)alloc((size_t)NS * 128 * 2);
  u16* Wp1  = (u16*)alloc((size_t)NK * 64 * 128 * 2);
  u16* Wp2  = (u16*)alloc((size_t)NK * 128 * 128 * 2);
  u16* Wpsc = (u16*)alloc((size_t)64 * 128 * 2);
  // d_out (102.4MB) hosts y1 bf16 (51.2MB) + fused gidx (21.6MB); k_final overwrites
  u16* Y1bf = (u16*)d_out;
  int* gidx = (int*)((char*)d_out + (size_t)NS * 128 * 2);
  float* part1 = (float*)Y2bf;          // dead region until conv2
  float* part2 = (float*)Xbf;           // Xbf dead after conv1

  hipLaunchKernelGGL(k_prep_x, dim3(50001), dim3(256), 0, stream, feats, Xbf, stats);
  hipLaunchKernelGGL(k_prep_gidx, dim3((NK * NS + 255) / 256), dim3(256), 0, stream,
                     in_idx, out_idx, gidx);
  hipLaunchKernelGGL(k_pack_w, dim3(2624), dim3(256), 0, stream, W1, W2, Wsc, Wp1, Wp2, Wpsc);
  hipLaunchKernelGGL((k_conv<64, true>), dim3(NB2), dim3(256), 0, stream,
                     Xbf, Wp1, Wpsc, gidx, Y1bf, SCbf, part1);
  hipLaunchKernelGGL(k_red1, dim3(2, 32), dim3(256), 0, stream, part1, rtmp, 512, NB2);
  hipLaunchKernelGGL(k_red2, dim3(2), dim3(256), 0, stream, rtmp, stats, 512);
  hipLaunchKernelGGL(k_bnrelu, dim3(12501), dim3(256), 0, stream, Y1bf, stats, g1, b1, Hbf);
  hipLaunchKernelGGL((k_conv<128, false>), dim3(NB2), dim3(256), 0, stream,
                     Hbf, Wp2, nullptr, gidx, Y2bf, nullptr, part2);
  hipLaunchKernelGGL(k_red1, dim3(1, 32), dim3(256), 0, stream, part2, rtmp, 256, NB2);
  hipLaunchKernelGGL(k_red2, dim3(1), dim3(256), 0, stream, rtmp, stats + 512, 256);
  hipLaunchKernelGGL(k_final, dim3(25000), dim3(256), 0, stream,
                     Y2bf, SCbf, stats, g2, b2, gsc, bsc, (float*)d_out);
}